// Round 7
// baseline (365.549 us; speedup 1.0000x reference)
//
#include <hip/hip_runtime.h>

typedef unsigned short u16;
typedef short s16x8 __attribute__((ext_vector_type(8)));
typedef _Float16 h16x8 __attribute__((ext_vector_type(8)));
typedef float f32x4 __attribute__((ext_vector_type(4)));
typedef u16 u16x4 __attribute__((ext_vector_type(4)));

#define DEV static __device__ __forceinline__

// ---------- f16 limb helpers (RTNE via v_cvt_f16_f32) ----------
DEV u16 f2h(float x){ union { _Float16 h; u16 u; } v; v.h = (_Float16)x; return v.u; }
DEV float h2f(u16 u){ union { u16 u; _Float16 h; } v; v.u = u; return (float)v.h; }
DEV void split_h(float x, u16& h, u16& l){
    h = f2h(x);
    l = f2h(x - h2f(h));
}
DEV h16x8 H8(s16x8 v){ union { s16x8 s; h16x8 h; } u; u.s = v; return u.h; }
DEV f32x4 mfma16(s16x8 a, s16x8 b, f32x4 c){
    return __builtin_amdgcn_mfma_f32_16x16x32_f16(H8(a), H8(b), c, 0, 0, 0);
}

// ---------- swizzles ----------
// t-layout [row][2048 m]: 8-chunk swizzle on m bits 3-5 (gemm LDS path)
DEV int swz(int r, int m){ return (m & ~0x38) | ((((m >> 3) ^ r) & 7) << 3); }
// G row-major [row][128]: 4-chunk swizzle on col bits 3-4, keyed by row
// bits 1-2 -> combine's linear LDS copy reads 2-way bank-aliased (free).
DEV int swzG(int row, int c){ return (c & ~0x18) | ((((c >> 3) ^ (row >> 1)) & 3) << 3); }

// global -> LDS direct (16B per lane)
DEV void gll16(const u16* g, u16* l){
    __builtin_amdgcn_global_load_lds((const __attribute__((address_space(1))) void*)g,
                                     (__attribute__((address_space(3))) void*)l, 16, 0, 0);
}

// =====================================================================
// K_prep (merged): blocks 0..2047 = supports softmax rows; rest = prep.
// =====================================================================
__global__ __launch_bounds__(256) void k_prep(const float* __restrict__ E,
    const float* __restrict__ gwp, const float* __restrict__ gbp,
    const float* __restrict__ uwp, const float* __restrict__ ubp,
    const float* __restrict__ x,   const float* __restrict__ state,
    const float* __restrict__ lw,
    u16* __restrict__ wg, u16* __restrict__ wu,
    float* __restrict__ bg, float* __restrict__ bu,
    u16* __restrict__ xt, u16* __restrict__ lwt,
    u16* __restrict__ Sh, u16* __restrict__ Sl)
{
    __shared__ float red[8];
    const int tid = threadIdx.x;
    if (blockIdx.x < 2048){
        // ---- supports row n -> hi/lo f16 limbs, chunk-swizzled ----
        const int n = blockIdx.x;
        const int w = tid >> 6, lane = tid & 63;
        float en[10];
        #pragma unroll
        for (int d = 0; d < 10; d++) en[d] = E[n*10 + d];
        float v[8];
        #pragma unroll
        for (int i = 0; i < 8; i++){
            int m = tid + i*256;
            const float* em = E + m*10;
            float s = 0.f;
            #pragma unroll
            for (int d = 0; d < 10; d++) s += en[d]*em[d];
            v[i] = fmaxf(s, 0.f);
        }
        float mx = v[0];
        #pragma unroll
        for (int i = 1; i < 8; i++) mx = fmaxf(mx, v[i]);
        #pragma unroll
        for (int off = 32; off > 0; off >>= 1) mx = fmaxf(mx, __shfl_xor(mx, off));
        if (lane == 0) red[w] = mx;
        __syncthreads();
        mx = fmaxf(fmaxf(red[0], red[1]), fmaxf(red[2], red[3]));
        __syncthreads();
        float sum = 0.f;
        #pragma unroll
        for (int i = 0; i < 8; i++){ v[i] = __expf(v[i] - mx); sum += v[i]; }
        #pragma unroll
        for (int off = 32; off > 0; off >>= 1) sum += __shfl_xor(sum, off);
        if (lane == 0) red[4 + w] = sum;
        __syncthreads();
        sum = red[4] + red[5] + red[6] + red[7];
        float inv = 1.f / sum;
        #pragma unroll
        for (int i = 0; i < 8; i++){
            float p = v[i] * inv;
            u16 h, l; split_h(p, h, l);
            int ms = swz(n, tid + i*256);
            Sh[n*2048 + ms] = h;
            Sl[n*2048 + ms] = l;
        }
        return;
    }
    long idx = (long)(blockIdx.x - 2048)*256 + tid;
    if (idx < 491520){                               // gate w -> [jc][d][128 o][32 k]
        int kk = (int)(idx & 31);
        int o  = (int)((idx >> 5) & 127);
        int r2 = (int)(idx >> 12);                   // 0..119
        int d = r2 % 10, jc = r2 / 10;
        int j = jc*32 + kk;                          // 0..383
        int k = j >> 7, i = j & 127;
        float v = gwp[(((d*3 + k)*128) + i)*128 + o];
        wg[idx] = f2h(v);
    } else if (idx < 737280){                        // upd w -> [jc][d][64 o][32 k]
        long t = idx - 491520;
        int kk = (int)(t & 31);
        int o  = (int)((t >> 5) & 63);
        int r2 = (int)(t >> 11);                     // 0..119
        int d = r2 % 10, jc = r2 / 10;
        int j = jc*32 + kk;
        int k = j >> 7, i = j & 127;
        float v = uwp[(((d*3 + k)*128) + i)*64 + o];
        wu[t] = f2h(v);
    } else if (idx < 999424){                        // bias_g [2048][128]
        long t = idx - 737280; int n = (int)(t >> 7), o = (int)(t & 127);
        float s = 0.f;
        #pragma unroll
        for (int d = 0; d < 10; d++) s += E[n*10+d]*gbp[d*128+o];
        bg[t] = s;
    } else if (idx < 1130496){                       // bias_u [2048][64]
        long t = idx - 999424; int n = (int)(t >> 6), o = (int)(t & 63);
        float s = 0.f;
        #pragma unroll
        for (int d = 0; d < 10; d++) s += E[n*10+d]*ubp[d*64+o];
        bu[t] = s;
    } else if (idx < 5324800){                       // X_gate^T pack (single f16, swz)
        long t = idx - 1130496;
        int colG = (int)(t >> 11), m = (int)(t & 2047);
        int b = colG >> 7, c = colG & 127;
        float v = (c < 64) ? x[((long)(b*2048)+m)*64 + c]
                           : state[((long)(b*2048)+m)*64 + c - 64];
        xt[(long)colG*2048 + swz(colG, m)] = f2h(v);
    } else if (idx < 5332992){                       // lin_w [64 o][128 k] -> f16
        long t = idx - 5324800;
        lwt[t] = f2h(lw[t]);
    }
}

// =====================================================================
// Diffusion GEMM (round-6 structure). Epilogue change: G output stored
// as ROW-MAJOR f16 hi/lo limb pair, chunk-swizzled via swzG -> combine
// stages it with linear global_load_lds (no VALU re-split). Split of the
// same f32 value the combine used to split -> combine A bit-identical.
// =====================================================================
template<int EPI>
__global__ __launch_bounds__(256) void k_gemm(
    const u16* __restrict__ Ah, const u16* __restrict__ Al,
    const u16* __restrict__ Bt,
    u16* __restrict__ Ot, u16* __restrict__ Gh, u16* __restrict__ Gl,
    const u16* __restrict__ Xt)
{
    __shared__ __attribute__((aligned(16))) u16 AsH[2][64*64];
    __shared__ __attribute__((aligned(16))) u16 AsL[2][64*64];
    __shared__ __attribute__((aligned(16))) u16 Bs[2][128*64];
    const int tid = threadIdx.x;
    // XCD-aware bijective tile mapping (8 XCDs x 8x8 sub-grid)
    const int xc = blockIdx.x & 7, ii = blockIdx.x >> 3;
    const int bm = ((xc & 3)*8 + (ii & 7)) << 6;     // 32 row-tiles
    const int bn = ((xc >> 2)*8 + (ii >> 3)) << 7;   // 16 col-tiles
    const int w = tid >> 6, lane = tid & 63;
    const int wm = (w & 1) << 5;                     // 32 rows per wave
    const int wn = (w >> 1) << 6;                    // 64 cols per wave
    const int lr = lane & 15, lk = lane >> 4;

    const int srow = tid >> 3, scol = (tid & 7) << 3;
    const long a0 = (long)(bm + srow)*2048 + scol;
    const long a1 = a0 + 32*2048;
    const long b0 = (long)(bn + srow)*2048 + scol;
    const long b1 = b0 + 32*2048;
    const long b2 = b0 + 64*2048;
    const long b3 = b0 + 96*2048;
    const int l0 = tid*8, l1 = tid*8 + 2048;

    const int c0 = (lk ^ (lr & 7)) << 3;
    const int c1 = c0 ^ 32;

#define STAGE(B, K) do { \
        gll16(Ah + a0 + (K), &AsH[B][l0]); \
        gll16(Ah + a1 + (K), &AsH[B][l1]); \
        gll16(Al + a0 + (K), &AsL[B][l0]); \
        gll16(Al + a1 + (K), &AsL[B][l1]); \
        gll16(Bt + b0 + (K), &Bs[B][l0]); \
        gll16(Bt + b1 + (K), &Bs[B][l1]); \
        gll16(Bt + b2 + (K), &Bs[B][l0 + 4096]); \
        gll16(Bt + b3 + (K), &Bs[B][l1 + 4096]); \
    } while(0)

    f32x4 acc[2][4];
    const f32x4 Z4 = {0.f, 0.f, 0.f, 0.f};
    #pragma unroll
    for (int i = 0; i < 2; i++)
        #pragma unroll
        for (int j = 0; j < 4; j++) acc[i][j] = Z4;

    STAGE(0, 0);
    __syncthreads();
    int cur = 0;
    for (int k0 = 0; k0 < 2048; k0 += 64){
        if (k0 + 64 < 2048) STAGE(cur ^ 1, k0 + 64);
        const u16* ah = AsH[cur];
        const u16* al = AsL[cur];
        const u16* bs = Bs[cur];
        #pragma unroll
        for (int s2 = 0; s2 < 2; s2++){
            const int cc = s2 ? c1 : c0;
            s16x8 bfv[4], af[2];
            #pragma unroll
            for (int ni = 0; ni < 4; ni++)
                bfv[ni] = *(const s16x8*)&bs[(wn + ni*16 + lr)*64 + cc];
            #pragma unroll
            for (int mi = 0; mi < 2; mi++)
                af[mi] = *(const s16x8*)&ah[(wm + mi*16 + lr)*64 + cc];
            #pragma unroll
            for (int mi = 0; mi < 2; mi++)
                #pragma unroll
                for (int ni = 0; ni < 4; ni++)
                    acc[mi][ni] = mfma16(af[mi], bfv[ni], acc[mi][ni]);
            #pragma unroll
            for (int mi = 0; mi < 2; mi++)
                af[mi] = *(const s16x8*)&al[(wm + mi*16 + lr)*64 + cc];
            #pragma unroll
            for (int mi = 0; mi < 2; mi++)
                #pragma unroll
                for (int ni = 0; ni < 4; ni++)
                    acc[mi][ni] = mfma16(af[mi], bfv[ni], acc[mi][ni]);
        }
        __syncthreads();
        cur ^= 1;
    }
#undef STAGE

    #pragma unroll
    for (int mi = 0; mi < 2; mi++){
        #pragma unroll
        for (int ni = 0; ni < 4; ni++){
            int i0 = bm + wm + mi*16 + lk*4;
            int j  = bn + wn + ni*16 + lr;
            f32x4 v = acc[mi][ni];
            if constexpr (EPI){
                u16x4 xh = *(const u16x4*)(Xt + (long)j*2048 + swz(j, i0));
                #pragma unroll
                for (int r = 0; r < 4; r++)
                    v[r] = 2.f*v[r] - h2f(xh[r]);
            }
            int bb = j >> 7, cc = j & 127;
            long gbase = ((long)bb*2048 + i0)*128;
            #pragma unroll
            for (int r = 0; r < 4; r++){
                int cs = swzG(i0 + r, cc);
                u16 gh, gl; split_h(v[r], gh, gl);
                Gh[gbase + (long)r*128 + cs] = gh;
                Gl[gbase + (long)r*128 + cs] = gl;
            }
            if constexpr (!EPI){
                u16x4 oh;
                #pragma unroll
                for (int r = 0; r < 4; r++) oh[r] = f2h(v[r]);
                *(u16x4*)(Ot + (long)j*2048 + swz(j, i0)) = oh;
            }
        }
    }
}

// =====================================================================
// Combine v5: round-4 proven d-loop kept verbatim. A staging reworked:
//  - double-buffered [2][64*32] LDS, ONE barrier per jc (was 2)
//  - jc>=4: A = G limb arrays, staged with 2 global_load_lds per thread
//    (zero VALU; swzG baked into global layout -> linear copy, 2-way
//    bank-free frag reads at chunk lk ^ ((lr>>1)&3))
//  - jc<4: f32 x/second VALU split path writing the SWIZZLED slot of
//    the idle buffer (no extra barrier)
//  - staging for jc+1 issued before jc's d-loop -> latency hides (T14)
// FUSE epilogue (gate: zr + candidate^T) unchanged from round 6.
// =====================================================================
template<int OFULL, int ACT, int FUSE>
__global__ __launch_bounds__(256, 2) void k_combine(
    const u16* __restrict__ G1h, const u16* __restrict__ G1l,
    const u16* __restrict__ G2h, const u16* __restrict__ G2l,
    const float* __restrict__ x, const float* __restrict__ second,
    const u16* __restrict__ W,
    const float* __restrict__ bias, const float* __restrict__ E,
    float* __restrict__ out, u16* __restrict__ XtT,
    const u16* __restrict__ lwt, const float* __restrict__ lb)
{
    constexpr int NO = OFULL/32;                 // o-frags per wave (4 gate, 2 upd)
    __shared__ __attribute__((aligned(16))) u16 Ash[2][64*32];
    __shared__ __attribute__((aligned(16))) u16 Asl[2][64*32];
    __shared__ float Et[640];
    __shared__ u16 Zh[FUSE ? 64*136 : 1];
    __shared__ u16 Zl[FUSE ? 64*136 : 1];
    const int tid = threadIdx.x, bid = blockIdx.x;
    const int b = bid >> 5, n0 = (bid & 31) << 6;
    const int w = tid >> 6, lane = tid & 63;
    const int wm = (w & 1)*32, wo = (w >> 1)*(OFULL/2);
    const int lr = lane & 15, lk = lane >> 4;

    for (int i = tid; i < 640; i += 256)
        Et[i] = E[(n0 + (i & 63))*10 + (i >> 6)];

    const f32x4 Z4 = {0.f, 0.f, 0.f, 0.f};
    f32x4 acc[2][NO];
    #pragma unroll
    for (int mi = 0; mi < 2; mi++)
        #pragma unroll
        for (int oi = 0; oi < NO; oi++) acc[mi][oi] = Z4;

    const long rowbase = (long)b*2048 + n0;
    const int laneoff = (wo + lr)*32 + lk*8;     // u16 offset within W tile

    // staging geometry: thread covers (row = tid>>2, chunk = tid&3)
    const int srow = tid >> 2, schunk = tid & 3;
    const int sg = (srow >> 1) & 3;
    const int sdstV = srow*32 + ((schunk ^ sg) << 3);   // VALU path: swizzled slot
    const int ldst  = tid*8;                            // gll path: linear copy

    // frag read chunk swizzle
    const int fco = (lk ^ ((lr >> 1) & 3)) << 3;

    // ---- stage A_jc (f32 sources, jc<4) into buf ----
    auto stageV = [&](int jc, int buf){
        int col0 = jc*32;
        const float* src = (col0 < 64) ? (x + rowbase*64 + col0)
                                       : (second + rowbase*64 + (col0 - 64));
        src += (long)srow*64 + schunk*8;
        f32x4 s0 = *(const f32x4*)src;
        f32x4 s1 = *(const f32x4*)(src + 4);
        s16x8 vh, vl;
        #pragma unroll
        for (int t = 0; t < 4; t++){ u16 h,l; split_h(s0[t],h,l); vh[t]=(short)h; vl[t]=(short)l; }
        #pragma unroll
        for (int t = 0; t < 4; t++){ u16 h,l; split_h(s1[t],h,l); vh[4+t]=(short)h; vl[4+t]=(short)l; }
        *(s16x8*)&Ash[buf][sdstV] = vh;
        *(s16x8*)&Asl[buf][sdstV] = vl;
    };
    // ---- stage A_jc (G limb arrays, jc>=4) into buf, async ----
    auto stageG = [&](int jc, int buf){
        const u16 *sh, *sl; int col0;
        if (jc < 8){ sh = G1h; sl = G1l; col0 = (jc-4)*32; }
        else       { sh = G2h; sl = G2l; col0 = (jc-8)*32; }
        long off = (rowbase + srow)*128 + col0 + schunk*8;
        gll16(sh + off, &Ash[buf][ldst]);
        gll16(sl + off, &Asl[buf][ldst]);
    };

    stageV(0, 0);
    __syncthreads();

    s16x8 pbh[3][NO];

    for (int jc = 0; jc < 12; jc++){
        const int cb = jc & 1;
        // W preload d=0,1 (longest-latency loads first)
        {
            const long t0 = (long)(jc*10 + 0)*OFULL*32;
            const long t1 = (long)(jc*10 + 1)*OFULL*32;
            #pragma unroll
            for (int oi = 0; oi < NO; oi++){
                pbh[0][oi] = *(const s16x8*)(W + t0 + laneoff + oi*16*32);
                pbh[1][oi] = *(const s16x8*)(W + t1 + laneoff + oi*16*32);
            }
        }
        // stage next jc into the idle buffer (async for G path)
        if (jc < 11){
            if (jc + 1 < 4) stageV(jc + 1, cb ^ 1);
            else            stageG(jc + 1, cb ^ 1);
        }
        // frag reads of current jc
        s16x8 ah[2], al[2];
        #pragma unroll
        for (int mi = 0; mi < 2; mi++){
            ah[mi] = *(const s16x8*)&Ash[cb][(wm + mi*16 + lr)*32 + fco];
            al[mi] = *(const s16x8*)&Asl[cb][(wm + mi*16 + lr)*32 + fco];
        }

        #pragma unroll
        for (int d = 0; d < 10; d++){
            const int cur = d % 3;               // compile-time after unroll
            if (d < 8){                          // prefetch d+2 into slot (d+2)%3
                const int nx = (d + 2) % 3;
                const long t2 = (long)(jc*10 + d + 2)*OFULL*32;
                #pragma unroll
                for (int oi = 0; oi < NO; oi++)
                    pbh[nx][oi] = *(const s16x8*)(W + t2 + laneoff + oi*16*32);
            }
            f32x4 Cd[2][NO];
            #pragma unroll
            for (int mi = 0; mi < 2; mi++)
                #pragma unroll
                for (int oi = 0; oi < NO; oi++)
                    Cd[mi][oi] = mfma16(ah[mi], pbh[cur][oi], Z4);
            #pragma unroll
            for (int mi = 0; mi < 2; mi++)
                #pragma unroll
                for (int oi = 0; oi < NO; oi++)
                    Cd[mi][oi] = mfma16(al[mi], pbh[cur][oi], Cd[mi][oi]);
            #pragma unroll
            for (int mi = 0; mi < 2; mi++){
                f32x4 e4 = *(const f32x4*)&Et[d*64 + wm + mi*16 + lk*4];
                #pragma unroll
                for (int oi = 0; oi < NO; oi++) acc[mi][oi] += e4 * Cd[mi][oi];
            }
        }
        __syncthreads();   // frag reads done + next buf's gll writes landed
    }

    if constexpr (!FUSE){
        #pragma unroll
        for (int mi = 0; mi < 2; mi++){
            #pragma unroll
            for (int oi = 0; oi < NO; oi++){
                int mrow = n0 + wm + mi*16 + lk*4;
                int o = wo + oi*16 + lr;
                #pragma unroll
                for (int r = 0; r < 4; r++){
                    float v = acc[mi][oi][r] + bias[(long)(mrow + r)*OFULL + o];
                    v = (ACT == 0) ? (1.f/(1.f + __expf(-v))) : tanhf(v);
                    out[((long)b*2048 + mrow + r)*OFULL + o] = v;
                }
            }
        }
    } else {
        // ---- fused: Zg = sigmoid(acc+bias) -> LDS limbs ----
        #pragma unroll
        for (int mi = 0; mi < 2; mi++){
            #pragma unroll
            for (int oi = 0; oi < NO; oi++){
                int lrow = wm + mi*16 + lk*4;
                int o = wo + oi*16 + lr;
                #pragma unroll
                for (int r = 0; r < 4; r++){
                    float v = acc[mi][oi][r] + bias[(long)(n0 + lrow + r)*OFULL + o];
                    v = 1.f/(1.f + __expf(-v));
                    u16 h, l; split_h(v, h, l);
                    Zh[(lrow + r)*136 + o] = h;
                    Zl[(lrow + r)*136 + o] = l;
                }
            }
        }
        __syncthreads();
        // ---- zr = Zg @ lw^T + lb ; wave w owns o-stripe w*16 ----
        f32x4 az[4];
        #pragma unroll
        for (int mi = 0; mi < 4; mi++) az[mi] = Z4;
        const int oz = w*16 + lr;
        #pragma unroll
        for (int ks = 0; ks < 4; ks++){
            s16x8 bw = *(const s16x8*)(lwt + oz*128 + ks*32 + lk*8);
            #pragma unroll
            for (int mi = 0; mi < 4; mi++){
                s16x8 zh = *(const s16x8*)&Zh[(mi*16 + lr)*136 + ks*32 + lk*8];
                az[mi] = mfma16(zh, bw, az[mi]);
            }
            #pragma unroll
            for (int mi = 0; mi < 4; mi++){
                s16x8 zl = *(const s16x8*)&Zl[(mi*16 + lr)*136 + ks*32 + lk*8];
                az[mi] = mfma16(zl, bw, az[mi]);
            }
        }
        const float lbv = lb[w*16 + lr];
        const int colG = b*128 + 64 + w*16 + lr;
        #pragma unroll
        for (int mi = 0; mi < 4; mi++){
            int mrow = n0 + mi*16 + lk*4;
            u16x4 tq;
            #pragma unroll
            for (int r = 0; r < 4; r++){
                float v = az[mi][r] + lbv;
                out[((long)b*2048 + mrow + r)*64 + w*16 + lr] = v;  // zr f32 rows
                tq[r] = f2h(v);
            }
            *(u16x4*)(XtT + (long)colG*2048 + swz(colG, mrow)) = tq; // candidate^T half
        }
    }
}

// =====================================================================
extern "C" void kernel_launch(void* const* d_in, const int* in_sizes, int n_in,
                              void* d_out, int out_size, void* d_ws, size_t ws_size,
                              hipStream_t stream)
{
    const float* x   = (const float*)d_in[0];
    const float* st  = (const float*)d_in[1];
    const float* E   = (const float*)d_in[2];
    const float* gwp = (const float*)d_in[3];
    const float* gbp = (const float*)d_in[4];
    const float* uwp = (const float*)d_in[5];
    const float* ubp = (const float*)d_in[6];
    const float* lw  = (const float*)d_in[7];
    const float* lb  = (const float*)d_in[8];
    float* out = (float*)d_out;
    char* ws = (char*)d_ws;

    const size_t MB8 = 8388608;
    u16*   Sh   = (u16*)(ws);                 // 8 MB
    u16*   Sl   = (u16*)(ws + 1*MB8);         // 8 MB
    u16*   Xt   = (u16*)(ws + 2*MB8);         // 8 MB (X^T gate -> candidate)
    u16*   G1t  = (u16*)(ws + 3*MB8);         // 8 MB
    u16*   G1h  = (u16*)(ws + 4*MB8);         // 8 MB (row-major limb, swzG)
    u16*   G1l  = (u16*)(ws + 5*MB8);         // 8 MB
    u16*   G2h  = (u16*)(ws + 6*MB8);         // 8 MB
    u16*   G2l  = (u16*)(ws + 7*MB8);         // 8 MB
    float* zr   = (float*)(ws + 8*MB8);       // 8 MB
    char*  p    = ws + 9*MB8;
    u16* wg = (u16*)p;             p += 983040;
    u16* wu = (u16*)p;             p += 491520;
    float* bg = (float*)p;         p += 1048576;
    float* bu = (float*)p;         p += 524288;
    u16* lwt = (u16*)p;            p += 16384;

    // merged supports (2048 blocks) + prep (20832 blocks)
    k_prep<<<dim3(22880), dim3(256), 0, stream>>>(E, gwp, gbp, uwp, ubp, x, st, lw,
                                                  wg, wu, bg, bu, Xt, lwt, Sh, Sl);
    // gate diffusion
    k_gemm<0><<<dim3(512), dim3(256), 0, stream>>>(Sh, Sl, Xt, G1t, G1h, G1l,
                                                   (const u16*)nullptr);
    k_gemm<1><<<dim3(512), dim3(256), 0, stream>>>(Sh, Sl, G1t, (u16*)nullptr,
                                                   G2h, G2l, Xt);
    // gate combine -> zr (fused lin) + candidate^T zr-half into Xt
    k_combine<128,0,1><<<dim3(512), dim3(256), 0, stream>>>(G1h, G1l, G2h, G2l,
                                                            x, st, wg, bg, E,
                                                            zr, Xt, lwt, lb);
    // update diffusion (Xt now = candidate^T)
    k_gemm<0><<<dim3(512), dim3(256), 0, stream>>>(Sh, Sl, Xt, G1t, G1h, G1l,
                                                   (const u16*)nullptr);
    k_gemm<1><<<dim3(512), dim3(256), 0, stream>>>(Sh, Sl, G1t, (u16*)nullptr,
                                                   G2h, G2l, Xt);
    // update combine -> out (tanh)
    k_combine<64,1,0><<<dim3(512), dim3(256), 0, stream>>>(G1h, G1l, G2h, G2l,
                                                           x, zr, wu, bu, E, out,
                                                           (u16*)nullptr,
                                                           (const u16*)nullptr,
                                                           (const float*)nullptr);
}